// Round 1
// baseline (260.730 us; speedup 1.0000x reference)
//
#include <hip/hip_runtime.h>

#define HCn 4
#define Cn 2048
#define Dn (HCn*Cn)       // 8192
#define NLg 24            // HC*HC + 2*HC
#define TMAXn 8
#define TOK 4

typedef short bf16x8 __attribute__((ext_vector_type(8)));
typedef float f32x4 __attribute__((ext_vector_type(4)));

__device__ __forceinline__ unsigned short f2bf(float f) {
  union { float f; unsigned int u; } v; v.f = f;
  unsigned int r = v.u + 0x7fffu + ((v.u >> 16) & 1u);
  return (unsigned short)(r >> 16);
}
__device__ __forceinline__ unsigned int pk2(float a, float b) {
  return (unsigned int)f2bf(a) | ((unsigned int)f2bf(b) << 16);
}
__device__ __forceinline__ float sigm(float z) { return 1.0f / (1.0f + expf(-z)); }

__device__ __forceinline__ void gload_lds16(const void* g, void* l) {
  __builtin_amdgcn_global_load_lds((__attribute__((address_space(1))) void*)(g),
                                   (__attribute__((address_space(3))) void*)(l),
                                   16, 0, 0);
}

// ---------------- Kernel 1: coeffs + x_in (TOK tokens per block) ----------------
__global__ __launch_bounds__(256) void coeffs_kernel(
    const float* __restrict__ x, const float* __restrict__ phi,
    const float* __restrict__ bb, const float* __restrict__ apre_p,
    const float* __restrict__ apost_p, const float* __restrict__ ares_p,
    unsigned int* __restrict__ xin,   // bf16-packed, C/2 uints per token
    float* __restrict__ hpost, float* __restrict__ hres) {
  int tid = threadIdx.x;
  int lane = tid & 63, wid = tid >> 6;
  long t0 = (long)blockIdx.x * TOK;
  const float4* xb4[TOK];
#pragma unroll
  for (int tk = 0; tk < TOK; ++tk) xb4[tk] = (const float4*)(x + (size_t)(t0 + tk) * Dn);
  const float4* phi4 = (const float4*)phi;

  float acc[TOK][NLg];
  float ss[TOK];
#pragma unroll
  for (int tk = 0; tk < TOK; ++tk) {
    ss[tk] = 0.f;
#pragma unroll
    for (int j = 0; j < NLg; ++j) acc[tk][j] = 0.f;
  }

  for (int i4 = tid; i4 < Dn / 4; i4 += 256) {
    float4 xv[TOK];
#pragma unroll
    for (int tk = 0; tk < TOK; ++tk) xv[tk] = xb4[tk][i4];
#pragma unroll
    for (int r = 0; r < 4; ++r) {
      float vr[TOK];
#pragma unroll
      for (int tk = 0; tk < TOK; ++tk) {
        float v = (r == 0) ? xv[tk].x : (r == 1) ? xv[tk].y : (r == 2) ? xv[tk].z : xv[tk].w;
        vr[tk] = v; ss[tk] += v * v;
      }
#pragma unroll
      for (int jj = 0; jj < 6; ++jj) {
        float4 p = phi4[(size_t)(i4 * 4 + r) * 6 + jj];
#pragma unroll
        for (int tk = 0; tk < TOK; ++tk) {
          acc[tk][jj * 4 + 0] += vr[tk] * p.x;
          acc[tk][jj * 4 + 1] += vr[tk] * p.y;
          acc[tk][jj * 4 + 2] += vr[tk] * p.z;
          acc[tk][jj * 4 + 3] += vr[tk] * p.w;
        }
      }
    }
  }

  __shared__ float red[4][TOK][NLg + 1];
  __shared__ float dots[TOK][NLg + 1];
  __shared__ float hpre_s[TOK][HCn];

#pragma unroll
  for (int tk = 0; tk < TOK; ++tk) {
#pragma unroll
    for (int j = 0; j < NLg; ++j) {
      float v = acc[tk][j];
      v += __shfl_xor(v, 1);  v += __shfl_xor(v, 2);  v += __shfl_xor(v, 4);
      v += __shfl_xor(v, 8);  v += __shfl_xor(v, 16); v += __shfl_xor(v, 32);
      if (lane == 0) red[wid][tk][j] = v;
    }
    float s = ss[tk];
    s += __shfl_xor(s, 1);  s += __shfl_xor(s, 2);  s += __shfl_xor(s, 4);
    s += __shfl_xor(s, 8);  s += __shfl_xor(s, 16); s += __shfl_xor(s, 32);
    if (lane == 0) red[wid][tk][NLg] = s;
  }
  __syncthreads();
  if (tid < TOK * (NLg + 1)) {
    int tk = tid / (NLg + 1), j = tid % (NLg + 1);
    dots[tk][j] = red[0][tk][j] + red[1][tk][j] + red[2][tk][j] + red[3][tk][j];
  }
  __syncthreads();
  if (tid < TOK) {
    int tk = tid;
    long t = t0 + tk;
    float apre = apre_p[0], apost = apost_p[0], ares = ares_p[0];
    float r = rsqrtf(dots[tk][NLg] / (float)Dn + 1e-6f);
    float lg[NLg];
#pragma unroll
    for (int j = 0; j < NLg; ++j) lg[j] = r * dots[tk][j] + bb[j];
#pragma unroll
    for (int j = 0; j < 4; ++j) hpre_s[tk][j] = sigm(apre * lg[j]) + 1e-4f;
#pragma unroll
    for (int j = 0; j < 4; ++j) hpost[t * 4 + j] = 2.0f * sigm(apost * lg[4 + j]);
    float m[16];
#pragma unroll
    for (int q = 0; q < 16; ++q) m[q] = expf(ares * lg[8 + q]);
    for (int it = 0; it < TMAXn; ++it) {
#pragma unroll
      for (int o = 0; o < 4; ++o) {
        float rs = m[o*4] + m[o*4+1] + m[o*4+2] + m[o*4+3] + 1e-6f;
        m[o*4] /= rs; m[o*4+1] /= rs; m[o*4+2] /= rs; m[o*4+3] /= rs;
      }
#pragma unroll
      for (int i = 0; i < 4; ++i) {
        float cs = m[i] + m[4+i] + m[8+i] + m[12+i] + 1e-6f;
        m[i] /= cs; m[4+i] /= cs; m[8+i] /= cs; m[12+i] /= cs;
      }
    }
#pragma unroll
    for (int q = 0; q < 16; ++q) hres[t * 16 + q] = m[q];
  }
  __syncthreads();

  // x_in = sum_hc h_pre[hc] * x[hc, :], stored bf16
#pragma unroll
  for (int tk = 0; tk < TOK; ++tk) {
    float h0 = hpre_s[tk][0], h1 = hpre_s[tk][1], h2 = hpre_s[tk][2], h3 = hpre_s[tk][3];
    const float4* xb = xb4[tk];
    unsigned int* xo = xin + (size_t)(t0 + tk) * (Cn / 2);
    for (int c4 = tid; c4 < Cn / 4; c4 += 256) {
      float4 v0 = xb[c4];
      float4 v1 = xb[c4 + (Cn / 4)];
      float4 v2 = xb[c4 + 2 * (Cn / 4)];
      float4 v3 = xb[c4 + 3 * (Cn / 4)];
      float sx = h0*v0.x + h1*v1.x + h2*v2.x + h3*v3.x;
      float sy = h0*v0.y + h1*v1.y + h2*v2.y + h3*v3.y;
      float sz = h0*v0.z + h1*v1.z + h2*v2.z + h3*v3.z;
      float sw = h0*v0.w + h1*v1.w + h2*v2.w + h3*v3.w;
      uint2 o; o.x = pk2(sx, sy); o.y = pk2(sz, sw);
      *(uint2*)&xo[c4 * 2] = o;
    }
  }
}

// ---------------- Kernel 2: W (K x N, f32) -> Wt (N x K, bf16) ----------------
__global__ __launch_bounds__(256) void wtrans_kernel(const float* __restrict__ W,
                                                     unsigned short* __restrict__ Wt) {
  __shared__ float tile[64][65];
  int kb = blockIdx.y * 64, nb = blockIdx.x * 64;
  int tr = threadIdx.x >> 4;   // 0..15
  int tc = threadIdx.x & 15;   // 0..15
#pragma unroll
  for (int rr = 0; rr < 64; rr += 16) {
    float4 v = *(const float4*)&W[(size_t)(kb + tr + rr) * Cn + nb + tc * 4];
    tile[tr + rr][tc * 4 + 0] = v.x; tile[tr + rr][tc * 4 + 1] = v.y;
    tile[tr + rr][tc * 4 + 2] = v.z; tile[tr + rr][tc * 4 + 3] = v.w;
  }
  __syncthreads();
#pragma unroll
  for (int rr = 0; rr < 64; rr += 16) {
    int n = nb + tr + rr;
    uint2 o;
    o.x = pk2(tile[tc * 4 + 0][tr + rr], tile[tc * 4 + 1][tr + rr]);
    o.y = pk2(tile[tc * 4 + 2][tr + rr], tile[tc * 4 + 3][tr + rr]);
    *(uint2*)&Wt[(size_t)n * Cn + kb + tc * 4] = o;
  }
}

// ---------------- Kernel 3: bf16 MFMA GEMM (x_in @ W) + fused epilogue ----------------
#define BMt 128
#define BNt 128
#define BKt 32
#define GK Cn
__global__ __launch_bounds__(256) void gemm_ep_kernel(
    const unsigned short* __restrict__ xin, const unsigned short* __restrict__ Wt,
    const float* __restrict__ x, const float* __restrict__ Wb,
    const float* __restrict__ hpost, const float* __restrict__ hres,
    float* __restrict__ out) {
  __shared__ __align__(16) unsigned short As[BMt * BKt];
  __shared__ __align__(16) unsigned short Bs[BNt * BKt];
  int tid = threadIdx.x;
  int lane = tid & 63, wid = tid >> 6;
  int wr = wid >> 1, wc = wid & 1;
  int l15 = lane & 15, l4 = lane >> 4;
  int bx = blockIdx.x, by = blockIdx.y;

  f32x4 acc[4][4];
#pragma unroll
  for (int i = 0; i < 4; ++i)
#pragma unroll
    for (int j = 0; j < 4; ++j) acc[i][j] = {0.f, 0.f, 0.f, 0.f};

  const char* Ab = (const char*)xin + (size_t)by * BMt * GK * 2;
  const char* Bb = (const char*)Wt + (size_t)bx * BNt * GK * 2;
  int off0 = tid * 16, off1 = tid * 16 + 4096;
  int row0 = off0 >> 6, colb0 = off0 & 63;
  int row1 = off1 >> 6, colb1 = off1 & 63;

  for (int k0 = 0; k0 < GK; k0 += BKt) {
    gload_lds16(Ab + (size_t)row0 * (GK * 2) + k0 * 2 + colb0, (char*)As + off0);
    gload_lds16(Ab + (size_t)row1 * (GK * 2) + k0 * 2 + colb1, (char*)As + off1);
    gload_lds16(Bb + (size_t)row0 * (GK * 2) + k0 * 2 + colb0, (char*)Bs + off0);
    gload_lds16(Bb + (size_t)row1 * (GK * 2) + k0 * 2 + colb1, (char*)Bs + off1);
    __syncthreads();
    bf16x8 af[4], bfv[4];
#pragma unroll
    for (int fm = 0; fm < 4; ++fm)
      af[fm] = *(const bf16x8*)&As[(wr * 64 + fm * 16 + l15) * BKt + l4 * 8];
#pragma unroll
    for (int fn = 0; fn < 4; ++fn)
      bfv[fn] = *(const bf16x8*)&Bs[(wc * 64 + fn * 16 + l15) * BKt + l4 * 8];
#pragma unroll
    for (int fm = 0; fm < 4; ++fm)
#pragma unroll
      for (int fn = 0; fn < 4; ++fn)
        acc[fm][fn] = __builtin_amdgcn_mfma_f32_16x16x32_bf16(af[fm], bfv[fn], acc[fm][fn], 0, 0, 0);
    __syncthreads();
  }

  // fused epilogue: out[t,o,c] = sum_i hres[t,o,i]*x[t,i,c] + hpost[t,o]*(f_out+Wb)
  int m0 = by * BMt + wr * 64;
  int n0 = bx * BNt + wc * 64;
#pragma unroll
  for (int fm = 0; fm < 4; ++fm) {
#pragma unroll
    for (int e = 0; e < 4; ++e) {
      int t = m0 + fm * 16 + l4 * 4 + e;
      const float* hr = hres + (size_t)t * 16;
      const float* hq = hpost + (size_t)t * 4;
      const float* xt = x + (size_t)t * Dn;
      float* ot = out + (size_t)t * Dn;
      float hr_[16], hq_[4];
#pragma unroll
      for (int q = 0; q < 16; ++q) hr_[q] = hr[q];
#pragma unroll
      for (int q = 0; q < 4; ++q) hq_[q] = hq[q];
#pragma unroll
      for (int fn = 0; fn < 4; ++fn) {
        int c = n0 + fn * 16 + l15;
        float f = acc[fm][fn][e] + Wb[c];
        float x0 = xt[c], x1 = xt[Cn + c], x2 = xt[2 * Cn + c], x3 = xt[3 * Cn + c];
#pragma unroll
        for (int o = 0; o < 4; ++o) {
          ot[(size_t)o * Cn + c] =
              hq_[o] * f + hr_[o*4+0] * x0 + hr_[o*4+1] * x1 + hr_[o*4+2] * x2 + hr_[o*4+3] * x3;
        }
      }
    }
  }
}

extern "C" void kernel_launch(void* const* d_in, const int* in_sizes, int n_in,
                              void* d_out, int out_size, void* d_ws, size_t ws_size,
                              hipStream_t stream) {
  const float* x     = (const float*)d_in[0];
  const float* phi   = (const float*)d_in[1];
  const float* b     = (const float*)d_in[2];
  const float* apre  = (const float*)d_in[3];
  const float* apost = (const float*)d_in[4];
  const float* ares  = (const float*)d_in[5];
  const float* W     = (const float*)d_in[6];
  const float* Wb    = (const float*)d_in[7];
  float* out = (float*)d_out;

  int NT = in_sizes[0] / Dn;   // B*S = 4096 tokens
  char* ws = (char*)d_ws;
  size_t xin_b = (size_t)NT * Cn * 2;        // 16 MB (bf16 x_in)
  size_t wt_b  = (size_t)Cn * Cn * 2;        // 8 MB  (bf16 W^T)
  unsigned int*   xin  = (unsigned int*)ws;
  unsigned short* Wt   = (unsigned short*)(ws + xin_b);
  float* hpost = (float*)(ws + xin_b + wt_b);
  float* hres  = (float*)(ws + xin_b + wt_b + (size_t)NT * 4 * 4);

  hipLaunchKernelGGL(coeffs_kernel, dim3(NT / TOK), dim3(256), 0, stream,
                     x, phi, b, apre, apost, ares, xin, hpost, hres);
  hipLaunchKernelGGL(wtrans_kernel, dim3(Cn / 64, Cn / 64), dim3(256), 0, stream, W, Wt);
  hipLaunchKernelGGL(gemm_ep_kernel, dim3(Cn / BNt, NT / BMt), dim3(256), 0, stream,
                     (const unsigned short*)xin, Wt, x, Wb, hpost, hres, out);
}

// Round 2
// 182.158 us; speedup vs baseline: 1.4313x; 1.4313x over previous
//
#include <hip/hip_runtime.h>

#define HCn 4
#define Cn 2048
#define Dn (HCn*Cn)       // 8192
#define NLg 24            // HC*HC + 2*HC
#define TMAXn 8
#define TOK 4

typedef short bf16x8 __attribute__((ext_vector_type(8)));
typedef float f32x4 __attribute__((ext_vector_type(4)));

__device__ __forceinline__ unsigned short f2bf(float f) {
  union { float f; unsigned int u; } v; v.f = f;
  unsigned int r = v.u + 0x7fffu + ((v.u >> 16) & 1u);
  return (unsigned short)(r >> 16);
}
__device__ __forceinline__ unsigned int pk2(float a, float b) {
  return (unsigned int)f2bf(a) | ((unsigned int)f2bf(b) << 16);
}
__device__ __forceinline__ float sigm(float z) { return 1.0f / (1.0f + expf(-z)); }

__device__ __forceinline__ void gload_lds16(const void* g, void* l) {
  __builtin_amdgcn_global_load_lds((__attribute__((address_space(1))) void*)(g),
                                   (__attribute__((address_space(3))) void*)(l),
                                   16, 0, 0);
}

// ---------------- Kernel 0: phi [8192][24] -> phiT [24][8192] (f32) ----------------
__global__ __launch_bounds__(256) void phit_kernel(const float* __restrict__ phi,
                                                   float* __restrict__ phiT) {
  __shared__ float t[256][25];
  int base = blockIdx.x * 256;  // row base
  for (int f = threadIdx.x; f < 256 * 24; f += 256) {
    t[f / 24][f % 24] = phi[(size_t)base * 24 + f];
  }
  __syncthreads();
#pragma unroll
  for (int j = 0; j < 24; ++j)
    phiT[(size_t)j * Dn + base + threadIdx.x] = t[threadIdx.x][j];
}

// ---------------- Kernel 1: coeffs + x_in (TOK tokens per block) ----------------
// Wave w owns phiT columns [6w, 6w+6); lanes sweep K coalesced.
__global__ __launch_bounds__(256) void coeffs_kernel(
    const float* __restrict__ x, const float* __restrict__ phiT,
    const float* __restrict__ bb, const float* __restrict__ apre_p,
    const float* __restrict__ apost_p, const float* __restrict__ ares_p,
    unsigned int* __restrict__ xin,   // bf16-packed, C/2 uints per token
    float* __restrict__ hpost, float* __restrict__ hres) {
  int tid = threadIdx.x;
  int lane = tid & 63, wid = tid >> 6;
  long t0 = (long)blockIdx.x * TOK;

  const float4* xb4[TOK];
#pragma unroll
  for (int tk = 0; tk < TOK; ++tk) xb4[tk] = (const float4*)(x + (size_t)(t0 + tk) * Dn);
  const float4* p4 = (const float4*)(phiT + (size_t)wid * 6 * Dn);  // 6 rows of 8192

  float acc[TOK][6];
  float ss[TOK];
#pragma unroll
  for (int tk = 0; tk < TOK; ++tk) {
    ss[tk] = 0.f;
#pragma unroll
    for (int j = 0; j < 6; ++j) acc[tk][j] = 0.f;
  }

  for (int i4 = lane; i4 < Dn / 4; i4 += 64) {
    float4 xv[TOK];
#pragma unroll
    for (int tk = 0; tk < TOK; ++tk) xv[tk] = xb4[tk][i4];
    if (wid == 0) {
#pragma unroll
      for (int tk = 0; tk < TOK; ++tk)
        ss[tk] += xv[tk].x * xv[tk].x + xv[tk].y * xv[tk].y +
                  xv[tk].z * xv[tk].z + xv[tk].w * xv[tk].w;
    }
#pragma unroll
    for (int j = 0; j < 6; ++j) {
      float4 p = p4[(size_t)j * (Dn / 4) + i4];
#pragma unroll
      for (int tk = 0; tk < TOK; ++tk) {
        acc[tk][j] += xv[tk].x * p.x + xv[tk].y * p.y + xv[tk].z * p.z + xv[tk].w * p.w;
      }
    }
  }

  __shared__ float dots[TOK][NLg + 1];
  __shared__ float hpre_s[TOK][HCn];

#pragma unroll
  for (int tk = 0; tk < TOK; ++tk) {
#pragma unroll
    for (int j = 0; j < 6; ++j) {
      float v = acc[tk][j];
      v += __shfl_xor(v, 1);  v += __shfl_xor(v, 2);  v += __shfl_xor(v, 4);
      v += __shfl_xor(v, 8);  v += __shfl_xor(v, 16); v += __shfl_xor(v, 32);
      if (lane == 0) dots[tk][wid * 6 + j] = v;
    }
  }
  if (wid == 0) {
#pragma unroll
    for (int tk = 0; tk < TOK; ++tk) {
      float s = ss[tk];
      s += __shfl_xor(s, 1);  s += __shfl_xor(s, 2);  s += __shfl_xor(s, 4);
      s += __shfl_xor(s, 8);  s += __shfl_xor(s, 16); s += __shfl_xor(s, 32);
      if (lane == 0) dots[tk][NLg] = s;
    }
  }
  __syncthreads();

  if (tid < TOK) {
    int tk = tid;
    long t = t0 + tk;
    float apre = apre_p[0], apost = apost_p[0], ares = ares_p[0];
    float r = rsqrtf(dots[tk][NLg] / (float)Dn + 1e-6f);
    float lg[NLg];
#pragma unroll
    for (int j = 0; j < NLg; ++j) lg[j] = r * dots[tk][j] + bb[j];
#pragma unroll
    for (int j = 0; j < 4; ++j) hpre_s[tk][j] = sigm(apre * lg[j]) + 1e-4f;
#pragma unroll
    for (int j = 0; j < 4; ++j) hpost[t * 4 + j] = 2.0f * sigm(apost * lg[4 + j]);
    float m[16];
#pragma unroll
    for (int q = 0; q < 16; ++q) m[q] = expf(ares * lg[8 + q]);
    for (int it = 0; it < TMAXn; ++it) {
#pragma unroll
      for (int o = 0; o < 4; ++o) {
        float rs = m[o*4] + m[o*4+1] + m[o*4+2] + m[o*4+3] + 1e-6f;
        m[o*4] /= rs; m[o*4+1] /= rs; m[o*4+2] /= rs; m[o*4+3] /= rs;
      }
#pragma unroll
      for (int i = 0; i < 4; ++i) {
        float cs = m[i] + m[4+i] + m[8+i] + m[12+i] + 1e-6f;
        m[i] /= cs; m[4+i] /= cs; m[8+i] /= cs; m[12+i] /= cs;
      }
    }
#pragma unroll
    for (int q = 0; q < 16; ++q) hres[t * 16 + q] = m[q];
  }
  __syncthreads();

  // x_in = sum_hc h_pre[hc] * x[hc, :], stored bf16
#pragma unroll
  for (int tk = 0; tk < TOK; ++tk) {
    float h0 = hpre_s[tk][0], h1 = hpre_s[tk][1], h2 = hpre_s[tk][2], h3 = hpre_s[tk][3];
    const float4* xb = xb4[tk];
    unsigned int* xo = xin + (size_t)(t0 + tk) * (Cn / 2);
    for (int c4 = tid; c4 < Cn / 4; c4 += 256) {
      float4 v0 = xb[c4];
      float4 v1 = xb[c4 + (Cn / 4)];
      float4 v2 = xb[c4 + 2 * (Cn / 4)];
      float4 v3 = xb[c4 + 3 * (Cn / 4)];
      float sx = h0*v0.x + h1*v1.x + h2*v2.x + h3*v3.x;
      float sy = h0*v0.y + h1*v1.y + h2*v2.y + h3*v3.y;
      float sz = h0*v0.z + h1*v1.z + h2*v2.z + h3*v3.z;
      float sw = h0*v0.w + h1*v1.w + h2*v2.w + h3*v3.w;
      uint2 o; o.x = pk2(sx, sy); o.y = pk2(sz, sw);
      *(uint2*)&xo[c4 * 2] = o;
    }
  }
}

// ---------------- Kernel 2: W (K x N, f32) -> Wt (N x K, bf16) ----------------
__global__ __launch_bounds__(256) void wtrans_kernel(const float* __restrict__ W,
                                                     unsigned short* __restrict__ Wt) {
  __shared__ float tile[64][65];
  int kb = blockIdx.y * 64, nb = blockIdx.x * 64;
  int tr = threadIdx.x >> 4;   // 0..15
  int tc = threadIdx.x & 15;   // 0..15
#pragma unroll
  for (int rr = 0; rr < 64; rr += 16) {
    float4 v = *(const float4*)&W[(size_t)(kb + tr + rr) * Cn + nb + tc * 4];
    tile[tr + rr][tc * 4 + 0] = v.x; tile[tr + rr][tc * 4 + 1] = v.y;
    tile[tr + rr][tc * 4 + 2] = v.z; tile[tr + rr][tc * 4 + 3] = v.w;
  }
  __syncthreads();
#pragma unroll
  for (int rr = 0; rr < 64; rr += 16) {
    int n = nb + tr + rr;
    uint2 o;
    o.x = pk2(tile[tc * 4 + 0][tr + rr], tile[tc * 4 + 1][tr + rr]);
    o.y = pk2(tile[tc * 4 + 2][tr + rr], tile[tc * 4 + 3][tr + rr]);
    *(uint2*)&Wt[(size_t)n * Cn + kb + tc * 4] = o;
  }
}

// ---------------- Kernel 3: bf16 MFMA GEMM (x_in @ W) + fused epilogue ----------------
#define BMt 128
#define BNt 128
#define BKt 32
#define GK Cn
__global__ __launch_bounds__(256) void gemm_ep_kernel(
    const unsigned short* __restrict__ xin, const unsigned short* __restrict__ Wt,
    const float* __restrict__ x, const float* __restrict__ Wb,
    const float* __restrict__ hpost, const float* __restrict__ hres,
    float* __restrict__ out) {
  __shared__ __align__(16) unsigned short As[BMt * BKt];
  __shared__ __align__(16) unsigned short Bs[BNt * BKt];
  int tid = threadIdx.x;
  int lane = tid & 63, wid = tid >> 6;
  int wr = wid >> 1, wc = wid & 1;
  int l15 = lane & 15, l4 = lane >> 4;
  int bx = blockIdx.x, by = blockIdx.y;

  f32x4 acc[4][4];
#pragma unroll
  for (int i = 0; i < 4; ++i)
#pragma unroll
    for (int j = 0; j < 4; ++j) acc[i][j] = {0.f, 0.f, 0.f, 0.f};

  const char* Ab = (const char*)xin + (size_t)by * BMt * GK * 2;
  const char* Bb = (const char*)Wt + (size_t)bx * BNt * GK * 2;
  int off0 = tid * 16, off1 = tid * 16 + 4096;
  int row0 = off0 >> 6, colb0 = off0 & 63;
  int row1 = off1 >> 6, colb1 = off1 & 63;

  for (int k0 = 0; k0 < GK; k0 += BKt) {
    gload_lds16(Ab + (size_t)row0 * (GK * 2) + k0 * 2 + colb0, (char*)As + off0);
    gload_lds16(Ab + (size_t)row1 * (GK * 2) + k0 * 2 + colb1, (char*)As + off1);
    gload_lds16(Bb + (size_t)row0 * (GK * 2) + k0 * 2 + colb0, (char*)Bs + off0);
    gload_lds16(Bb + (size_t)row1 * (GK * 2) + k0 * 2 + colb1, (char*)Bs + off1);
    __syncthreads();
    bf16x8 af[4], bfv[4];
#pragma unroll
    for (int fm = 0; fm < 4; ++fm)
      af[fm] = *(const bf16x8*)&As[(wr * 64 + fm * 16 + l15) * BKt + l4 * 8];
#pragma unroll
    for (int fn = 0; fn < 4; ++fn)
      bfv[fn] = *(const bf16x8*)&Bs[(wc * 64 + fn * 16 + l15) * BKt + l4 * 8];
#pragma unroll
    for (int fm = 0; fm < 4; ++fm)
#pragma unroll
      for (int fn = 0; fn < 4; ++fn)
        acc[fm][fn] = __builtin_amdgcn_mfma_f32_16x16x32_bf16(af[fm], bfv[fn], acc[fm][fn], 0, 0, 0);
    __syncthreads();
  }

  // fused epilogue: out[t,o,c] = sum_i hres[t,o,i]*x[t,i,c] + hpost[t,o]*(f_out+Wb)
  int m0 = by * BMt + wr * 64;
  int n0 = bx * BNt + wc * 64;
#pragma unroll
  for (int fm = 0; fm < 4; ++fm) {
#pragma unroll
    for (int e = 0; e < 4; ++e) {
      int t = m0 + fm * 16 + l4 * 4 + e;
      const float* hr = hres + (size_t)t * 16;
      const float* hq = hpost + (size_t)t * 4;
      const float* xt = x + (size_t)t * Dn;
      float* ot = out + (size_t)t * Dn;
      float hr_[16], hq_[4];
#pragma unroll
      for (int q = 0; q < 16; ++q) hr_[q] = hr[q];
#pragma unroll
      for (int q = 0; q < 4; ++q) hq_[q] = hq[q];
#pragma unroll
      for (int fn = 0; fn < 4; ++fn) {
        int c = n0 + fn * 16 + l15;
        float f = acc[fm][fn][e] + Wb[c];
        float x0 = xt[c], x1 = xt[Cn + c], x2 = xt[2 * Cn + c], x3 = xt[3 * Cn + c];
#pragma unroll
        for (int o = 0; o < 4; ++o) {
          ot[(size_t)o * Cn + c] =
              hq_[o] * f + hr_[o*4+0] * x0 + hr_[o*4+1] * x1 + hr_[o*4+2] * x2 + hr_[o*4+3] * x3;
        }
      }
    }
  }
}

extern "C" void kernel_launch(void* const* d_in, const int* in_sizes, int n_in,
                              void* d_out, int out_size, void* d_ws, size_t ws_size,
                              hipStream_t stream) {
  const float* x     = (const float*)d_in[0];
  const float* phi   = (const float*)d_in[1];
  const float* b     = (const float*)d_in[2];
  const float* apre  = (const float*)d_in[3];
  const float* apost = (const float*)d_in[4];
  const float* ares  = (const float*)d_in[5];
  const float* W     = (const float*)d_in[6];
  const float* Wb    = (const float*)d_in[7];
  float* out = (float*)d_out;

  int NT = in_sizes[0] / Dn;   // B*S = 4096 tokens
  char* ws = (char*)d_ws;
  size_t xin_b = (size_t)NT * Cn * 2;        // 16 MB (bf16 x_in)
  size_t wt_b  = (size_t)Cn * Cn * 2;        // 8 MB  (bf16 W^T)
  size_t hp_b  = (size_t)NT * 4 * 4;
  size_t hr_b  = (size_t)NT * 16 * 4;
  unsigned int*   xin  = (unsigned int*)ws;
  unsigned short* Wt   = (unsigned short*)(ws + xin_b);
  float* hpost = (float*)(ws + xin_b + wt_b);
  float* hres  = (float*)(ws + xin_b + wt_b + hp_b);
  float* phiT  = (float*)(ws + xin_b + wt_b + hp_b + hr_b);

  hipLaunchKernelGGL(phit_kernel, dim3(Dn / 256), dim3(256), 0, stream, phi, phiT);
  hipLaunchKernelGGL(coeffs_kernel, dim3(NT / TOK), dim3(256), 0, stream,
                     x, phiT, b, apre, apost, ares, xin, hpost, hres);
  hipLaunchKernelGGL(wtrans_kernel, dim3(Cn / 64, Cn / 64), dim3(256), 0, stream, W, Wt);
  hipLaunchKernelGGL(gemm_ep_kernel, dim3(Cn / BNt, NT / BMt), dim3(256), 0, stream,
                     (const unsigned short*)xin, Wt, x, Wb, hpost, hres, out);
}